// Round 1
// baseline (140.872 us; speedup 1.0000x reference)
//
#include <hip/hip_runtime.h>
#include <hip/hip_bf16.h>

#define CANVAS 512
#define PLANE (CANVAS * CANVAS)   // 262144 cells per batch
#define GRIDW 513                 // wrap modulus (pseudo_image_dims + 1)
#define BATCH 2
#define N_LI 1000000
#define N_RA 500000

// ---------------------------------------------------------------------------
// Kernel 1: zero the dyn plane (workspace is poisoned 0xAA before every call)
__global__ void zero_dyn(uint32_t* __restrict__ p, int nwords) {
    int i = blockIdx.x * blockDim.x + threadIdx.x;
    if (i < nwords) p[i] = 0u;
}

// ---------------------------------------------------------------------------
// Kernel 2: ra points — write ra_dy / ra_ind outputs and scatter dyn flags.
// segment_max(|vr|) > 0.1  ==  OR over points of (|vr| > 0.1): benign-race
// byte store of 1, no atomics needed.
__global__ void ra_kernel(const float* __restrict__ ra_input,
                          const int*   __restrict__ ra_coords,
                          int* __restrict__ ra_dy_out,
                          int* __restrict__ ra_ind_out,
                          unsigned char* __restrict__ dyn) {
    int idx = blockIdx.x * blockDim.x + threadIdx.x;
    if (idx >= BATCH * N_RA) return;
    float vr = fabsf(ra_input[(size_t)idx * 5 + 4]);
    int2 c = ((const int2*)ra_coords)[idx];     // (y, x)
    int flat = c.x * CANVAS + c.y;              // y*X + x
    int dy = (vr > 0.1f) ? 1 : 0;
    ra_dy_out[idx]  = dy;
    ra_ind_out[idx] = flat;
    if (dy) {
        int b = idx / N_RA;
        dyn[(size_t)b * PLANE + flat] = 1;
    }
}

// ---------------------------------------------------------------------------
// Kernel 3: 5x5 dilation with the reference's mod-513 wrap quirk.
// Forward: target t = (src + off) mod 513, dropped when t == 512.
// Inverse per target cell t: src = (t - off) mod 513, valid iff src < 512.
__global__ void dilate_kernel(const unsigned char* __restrict__ dyn,
                              unsigned char* __restrict__ neigh) {
    int idx = blockIdx.x * blockDim.x + threadIdx.x;
    if (idx >= BATCH * PLANE) return;
    int b    = idx / PLANE;
    int cell = idx - b * PLANE;
    int ty = cell >> 9;          // /512
    int tx = cell & (CANVAS - 1);
    const unsigned char* d = dyn + (size_t)b * PLANE;

    int sys[5]; int nsy = 0;
    int sxs[5]; int nsx = 0;
#pragma unroll
    for (int off = -2; off <= 2; ++off) {
        int sy = ty - off;
        if (sy < 0) sy += GRIDW;
        if (sy >= GRIDW) sy -= GRIDW;
        if (sy < CANVAS) { sys[nsy++] = sy; }
        int sx = tx - off;
        if (sx < 0) sx += GRIDW;
        if (sx >= GRIDW) sx -= GRIDW;
        if (sx < CANVAS) { sxs[nsx++] = sx; }
    }
    int acc = 0;
    for (int a = 0; a < nsy; ++a) {
        int base = sys[a] * CANVAS;
        for (int c2 = 0; c2 < nsx; ++c2) acc |= d[base + sxs[c2]];
    }
    neigh[idx] = (unsigned char)(acc ? 1 : 0);
}

// ---------------------------------------------------------------------------
// Kernel 4: li points — li_ind = flat index, li_dy = gather from neigh mask.
__global__ void li_kernel(const int* __restrict__ li_coords,
                          const unsigned char* __restrict__ neigh,
                          int* __restrict__ li_dy_out,
                          int* __restrict__ li_ind_out) {
    int idx = blockIdx.x * blockDim.x + threadIdx.x;
    if (idx >= BATCH * N_LI) return;
    int2 c = ((const int2*)li_coords)[idx];     // (y, x)
    int flat = c.x * CANVAS + c.y;
    int b = idx / N_LI;
    li_ind_out[idx] = flat;
    li_dy_out[idx]  = neigh[(size_t)b * PLANE + flat] ? 1 : 0;
}

// ---------------------------------------------------------------------------
extern "C" void kernel_launch(void* const* d_in, const int* in_sizes, int n_in,
                              void* d_out, int out_size, void* d_ws, size_t ws_size,
                              hipStream_t stream) {
    // inputs (setup_inputs order):
    // 0: li_input  (B,N_LI,4) f32   -- unused (shape-only in reference)
    // 1: li_coords (B,N_LI,2) i32
    // 2: li_point_idxes              -- identity, unused
    // 3: ra_input  (B,N_RA,5) f32   -- only column 4 used
    // 4: ra_coords (B,N_RA,2) i32
    // 5: ra_point_idxes              -- identity, unused
    const int*   li_coords = (const int*)d_in[1];
    const float* ra_input  = (const float*)d_in[3];
    const int*   ra_coords = (const int*)d_in[4];

    // outputs concatenated in return order, promoted dtype int32:
    // li_dy (B,N_LI), li_ind (B,N_LI), ra_dy (B,N_RA), ra_ind (B,N_RA)
    int* out        = (int*)d_out;
    int* li_dy_out  = out;
    int* li_ind_out = out + (size_t)BATCH * N_LI;
    int* ra_dy_out  = out + (size_t)2 * BATCH * N_LI;
    int* ra_ind_out = out + (size_t)2 * BATCH * N_LI + (size_t)BATCH * N_RA;

    unsigned char* dyn   = (unsigned char*)d_ws;           // B*PLANE bytes
    unsigned char* neigh = dyn + (size_t)BATCH * PLANE;    // B*PLANE bytes

    const int nwords = BATCH * PLANE / 4;
    zero_dyn<<<(nwords + 255) / 256, 256, 0, stream>>>((uint32_t*)dyn, nwords);
    ra_kernel<<<(BATCH * N_RA + 255) / 256, 256, 0, stream>>>(
        ra_input, ra_coords, ra_dy_out, ra_ind_out, dyn);
    dilate_kernel<<<(BATCH * PLANE + 255) / 256, 256, 0, stream>>>(dyn, neigh);
    li_kernel<<<(BATCH * N_LI + 255) / 256, 256, 0, stream>>>(
        li_coords, neigh, li_dy_out, li_ind_out);
}